// Round 1
// baseline (81.253 us; speedup 1.0000x reference)
//
#include <hip/hip_runtime.h>

#define CIN  256
#define COUT 256
#define BSZ  2
#define HH   48
#define WW   48
#define S    (HH * WW)   // 2304
#define KWIN 7
#define PADV 3

// ---------------- Phase 1: Out[m][b][o][s] = sum_c W_m[o][c] * X[b][c][s] ----------------
// 64x64 output tile per block, 256 threads, 4x4 micro-tile per thread, K-chunks of 16.
__global__ __launch_bounds__(256) void qkv_gemm(
    const float* __restrict__ x,
    const float* __restrict__ wq,
    const float* __restrict__ wk,
    const float* __restrict__ wv,
    float* __restrict__ qout,   // [B][O][S]
    float* __restrict__ kout,
    float* __restrict__ vout)
{
    __shared__ float Xs[16][64];
    __shared__ float Ws[16][64];
    const int t  = threadIdx.x;
    const int s0 = blockIdx.x * 64;
    const int o0 = blockIdx.y * 64;
    const int bm = blockIdx.z;          // b*3 + m
    const int b = bm / 3, m = bm % 3;
    const float* wmat = (m == 0) ? wq : (m == 1 ? wk : wv);
    float* outp       = (m == 0) ? qout : (m == 1 ? kout : vout);

    const int s4 = t & 15;   // s group (4 consecutive s each)
    const int o4 = t >> 4;   // o group (4 consecutive o each)
    float acc[4][4] = {};
    const float* xb = x + (size_t)b * CIN * S;

    for (int c0 = 0; c0 < CIN; c0 += 16) {
        // stage X[c0+cc][s0..s0+63]
        float4 xv = *(const float4*)(xb + (size_t)(c0 + (t >> 4)) * S + s0 + (t & 15) * 4);
        *(float4*)&Xs[t >> 4][(t & 15) * 4] = xv;
        // stage W transposed: Ws[c][o]; o = o0 + t/4, c = c0 + (t&3)*4 .. +3
        float4 wv4 = *(const float4*)(wmat + (size_t)(o0 + (t >> 2)) * CIN + c0 + (t & 3) * 4);
        Ws[(t & 3) * 4 + 0][t >> 2] = wv4.x;
        Ws[(t & 3) * 4 + 1][t >> 2] = wv4.y;
        Ws[(t & 3) * 4 + 2][t >> 2] = wv4.z;
        Ws[(t & 3) * 4 + 3][t >> 2] = wv4.w;
        __syncthreads();
#pragma unroll
        for (int c = 0; c < 16; ++c) {
            float4 wf = *(const float4*)&Ws[c][o4 * 4];
            float4 xf = *(const float4*)&Xs[c][s4 * 4];
            float wa[4] = {wf.x, wf.y, wf.z, wf.w};
            float xa[4] = {xf.x, xf.y, xf.z, xf.w};
#pragma unroll
            for (int i = 0; i < 4; ++i)
#pragma unroll
                for (int j = 0; j < 4; ++j)
                    acc[i][j] = fmaf(wa[i], xa[j], acc[i][j]);
        }
        __syncthreads();
    }
    float* op = outp + (size_t)b * COUT * S;
#pragma unroll
    for (int i = 0; i < 4; ++i) {
        float4 r = make_float4(acc[i][0], acc[i][1], acc[i][2], acc[i][3]);
        *(float4*)(op + (size_t)(o0 + o4 * 4 + i) * S + s0 + s4 * 4) = r;
    }
}

// ---------------- Phase 2: windowed per-channel softmax-attention ----------------
// One thread per (b,o,h,w); online softmax over the 7x7 window.
__global__ __launch_bounds__(192) void attn_win(
    const float* __restrict__ qmap,   // [B*O][S] (lives in d_out)
    const float* __restrict__ kmap,   // [B*O][S]
    const float* __restrict__ vmap,   // [B*O][S]
    const float* __restrict__ rel_h,  // [128*7]
    const float* __restrict__ rel_w,  // [128*7]
    float* __restrict__ out)          // [B*O][S] (same buffer as qmap)
{
    const int t  = threadIdx.x;
    const int w  = t % 48;
    const int h  = blockIdx.x * 4 + t / 48;
    const int bo = blockIdx.y;          // b*256 + o
    const int o  = bo & 255;
    const float* kp = kmap + (size_t)bo * S;
    const float* vp = vmap + (size_t)bo * S;

    const bool ish = (o < 128);
    const float* rp = ish ? (rel_h + o * 7) : (rel_w + (o - 128) * 7);
    float rel[7];
#pragma unroll
    for (int i = 0; i < 7; ++i) rel[i] = rp[i];

    const float q = qmap[(size_t)bo * S + h * WW + w];

    float mval = -3.0e38f, l = 0.f, acc = 0.f;
#pragma unroll
    for (int kh = 0; kh < KWIN; ++kh) {
        const int hh = h + kh - PADV;
        const bool hok = (unsigned)hh < (unsigned)HH;
#pragma unroll
        for (int kw = 0; kw < KWIN; ++kw) {
            const int ww = w + kw - PADV;
            const bool ok = hok && ((unsigned)ww < (unsigned)WW);
            const float kv = (ok ? kp[hh * WW + ww] : 0.f) + (ish ? rel[kh] : rel[kw]);
            const float vv =  ok ? vp[hh * WW + ww] : 0.f;
            const float sc = q * kv;
            const float mn = fmaxf(mval, sc);
            const float scale = __expf(mval - mn);   // first iter: exp(-huge) = 0
            const float p     = __expf(sc - mn);
            l   = l   * scale + p;
            acc = acc * scale + p * vv;
            mval = mn;
        }
    }
    out[(size_t)bo * S + h * WW + w] = acc / l;
}

extern "C" void kernel_launch(void* const* d_in, const int* in_sizes, int n_in,
                              void* d_out, int out_size, void* d_ws, size_t ws_size,
                              hipStream_t stream) {
    const float* x     = (const float*)d_in[0];
    const float* wq    = (const float*)d_in[1];
    const float* wk    = (const float*)d_in[2];
    const float* wv    = (const float*)d_in[3];
    const float* rel_h = (const float*)d_in[4];
    const float* rel_w = (const float*)d_in[5];
    float* out  = (float*)d_out;
    float* kbuf = (float*)d_ws;                       // [B][O][S]
    float* vbuf = kbuf + (size_t)BSZ * COUT * S;      // [B][O][S]  (needs 2*4.7MB in ws)

    dim3 g1(S / 64, COUT / 64, BSZ * 3);              // (36, 4, 6)
    qkv_gemm<<<g1, 256, 0, stream>>>(x, wq, wk, wv, out, kbuf, vbuf);

    dim3 g2(HH / 4, BSZ * COUT);                      // (12, 512)
    attn_win<<<g2, 192, 0, stream>>>(out, kbuf, vbuf, rel_h, rel_w, out);
}

// Round 2
// 53.591 us; speedup vs baseline: 1.5162x; 1.5162x over previous
//
#include <hip/hip_runtime.h>

#define CIN  256
#define COUT 256
#define BSZ  2
#define HH   48
#define WW   48
#define S    (HH * WW)   // 2304
#define KWIN 7
#define PADV 3

// ---------------- Phase 1: Out[m][b][o][s] = sum_c W_m[o][c] * X[b][c][s] ----------------
// 64x64 output tile per block, 256 threads, 4x4 micro-tile per thread, K-chunks of 16.
__global__ __launch_bounds__(256) void qkv_gemm(
    const float* __restrict__ x,
    const float* __restrict__ wq,
    const float* __restrict__ wk,
    const float* __restrict__ wv,
    float* __restrict__ qout,   // [B][O][S]
    float* __restrict__ kout,
    float* __restrict__ vout)
{
    __shared__ float Xs[16][64];
    __shared__ float Ws[16][64];
    const int t  = threadIdx.x;
    const int s0 = blockIdx.x * 64;
    const int o0 = blockIdx.y * 64;
    const int bm = blockIdx.z;          // b*3 + m
    const int b = bm / 3, m = bm % 3;
    const float* wmat = (m == 0) ? wq : (m == 1 ? wk : wv);
    float* outp       = (m == 0) ? qout : (m == 1 ? kout : vout);

    const int s4 = t & 15;   // s group (4 consecutive s each)
    const int o4 = t >> 4;   // o group (4 consecutive o each)
    float acc[4][4] = {};
    const float* xb = x + (size_t)b * CIN * S;

    for (int c0 = 0; c0 < CIN; c0 += 16) {
        // stage X[c0+cc][s0..s0+63]
        float4 xv = *(const float4*)(xb + (size_t)(c0 + (t >> 4)) * S + s0 + (t & 15) * 4);
        *(float4*)&Xs[t >> 4][(t & 15) * 4] = xv;
        // stage W transposed: Ws[c][o]; o = o0 + t/4, c = c0 + (t&3)*4 .. +3
        float4 wv4 = *(const float4*)(wmat + (size_t)(o0 + (t >> 2)) * CIN + c0 + (t & 3) * 4);
        Ws[(t & 3) * 4 + 0][t >> 2] = wv4.x;
        Ws[(t & 3) * 4 + 1][t >> 2] = wv4.y;
        Ws[(t & 3) * 4 + 2][t >> 2] = wv4.z;
        Ws[(t & 3) * 4 + 3][t >> 2] = wv4.w;
        __syncthreads();
#pragma unroll
        for (int c = 0; c < 16; ++c) {
            float4 wf = *(const float4*)&Ws[c][o4 * 4];
            float4 xf = *(const float4*)&Xs[c][s4 * 4];
            float wa[4] = {wf.x, wf.y, wf.z, wf.w};
            float xa[4] = {xf.x, xf.y, xf.z, xf.w};
#pragma unroll
            for (int i = 0; i < 4; ++i)
#pragma unroll
                for (int j = 0; j < 4; ++j)
                    acc[i][j] = fmaf(wa[i], xa[j], acc[i][j]);
        }
        __syncthreads();
    }
    float* op = outp + (size_t)b * COUT * S;
#pragma unroll
    for (int i = 0; i < 4; ++i) {
        float4 r = make_float4(acc[i][0], acc[i][1], acc[i][2], acc[i][3]);
        *(float4*)(op + (size_t)(o0 + o4 * 4 + i) * S + s0 + s4 * 4) = r;
    }
}

// ---------------- Phase 2: windowed per-channel softmax-attention ----------------
// Block = 4 rows x 48 cols of one (b,o) plane. Zero-padded LDS halo (10x56) for k,v:
// out-of-range positions read kv=0, v=0 => p=exp(q*rel) contributes to denom only,
// exactly matching the reference (bias added at padded positions, v window = 0).
// No max-subtraction: |score| << 88 so fp32 exp cannot overflow; softmax is
// shift-invariant so the result is identical up to rounding.
__global__ __launch_bounds__(192) void attn_win(
    const float* __restrict__ qmap,   // [B*O][S] (lives in d_out)
    const float* __restrict__ kmap,   // [B*O][S]
    const float* __restrict__ vmap,   // [B*O][S]
    const float* __restrict__ rel_h,  // [128*7]
    const float* __restrict__ rel_w,  // [128*7]
    float* __restrict__ out)          // [B*O][S] (same buffer as qmap)
{
    __shared__ float Ks[10][56];
    __shared__ float Vs[10][56];
    const int t  = threadIdx.x;
    const int h0 = blockIdx.x * 4;
    const int bo = blockIdx.y;          // b*256 + o
    const int o  = bo & 255;
    const float* kp = kmap + (size_t)bo * S;
    const float* vp = vmap + (size_t)bo * S;

    // stage rows h0-3..h0+6, cols -3..52 (col idx = ww+3); zeros outside the plane
#pragma unroll
    for (int i = t; i < 560; i += 192) {
        const int row = i / 56, col = i - row * 56;
        const int hh = h0 - 3 + row, ww = col - 3;
        const bool ok = ((unsigned)hh < (unsigned)HH) && ((unsigned)ww < (unsigned)WW);
        Ks[row][col] = ok ? kp[hh * WW + ww] : 0.f;
        Vs[row][col] = ok ? vp[hh * WW + ww] : 0.f;
    }

    const int w = t % 48;
    const int r = t / 48;
    const int h = h0 + r;
    const float q = qmap[(size_t)bo * S + h * WW + w];
    const bool ish = (o < 128);
    const float* rp = ish ? (rel_h + o * 7) : (rel_w + (o - 128) * 7);
    float qr[7];
#pragma unroll
    for (int i = 0; i < 7; ++i) qr[i] = q * rp[i];

    __syncthreads();

    float l[2] = {0.f, 0.f}, a[2] = {0.f, 0.f};
    if (ish) {
#pragma unroll
        for (int kh = 0; kh < KWIN; ++kh) {
            const float bb = qr[kh];
            const float* kr = &Ks[r + kh][w];
            const float* vr = &Vs[r + kh][w];
#pragma unroll
            for (int kw = 0; kw < KWIN; ++kw) {
                const float p = __expf(fmaf(q, kr[kw], bb));
                l[kw & 1] += p;
                a[kw & 1] = fmaf(p, vr[kw], a[kw & 1]);
            }
        }
    } else {
#pragma unroll
        for (int kh = 0; kh < KWIN; ++kh) {
            const float* kr = &Ks[r + kh][w];
            const float* vr = &Vs[r + kh][w];
#pragma unroll
            for (int kw = 0; kw < KWIN; ++kw) {
                const float p = __expf(fmaf(q, kr[kw], qr[kw]));
                l[kw & 1] += p;
                a[kw & 1] = fmaf(p, vr[kw], a[kw & 1]);
            }
        }
    }
    out[(size_t)bo * S + h * WW + w] = (a[0] + a[1]) / (l[0] + l[1]);
}

extern "C" void kernel_launch(void* const* d_in, const int* in_sizes, int n_in,
                              void* d_out, int out_size, void* d_ws, size_t ws_size,
                              hipStream_t stream) {
    const float* x     = (const float*)d_in[0];
    const float* wq    = (const float*)d_in[1];
    const float* wk    = (const float*)d_in[2];
    const float* wv    = (const float*)d_in[3];
    const float* rel_h = (const float*)d_in[4];
    const float* rel_w = (const float*)d_in[5];
    float* out  = (float*)d_out;
    float* kbuf = (float*)d_ws;                       // [B][O][S]
    float* vbuf = kbuf + (size_t)BSZ * COUT * S;      // [B][O][S]

    dim3 g1(S / 64, COUT / 64, BSZ * 3);              // (36, 4, 6)
    qkv_gemm<<<g1, 256, 0, stream>>>(x, wq, wk, wv, out, kbuf, vbuf);

    dim3 g2(HH / 4, BSZ * COUT);                      // (12, 512)
    attn_win<<<g2, 192, 0, stream>>>(out, kbuf, vbuf, rel_h, rel_w, out);
}

// Round 3
// 51.275 us; speedup vs baseline: 1.5847x; 1.0452x over previous
//
#include <hip/hip_runtime.h>

#define CIN  256
#define COUT 256
#define BSZ  2
#define HH   48
#define WW   48
#define S    (HH * WW)   // 2304
#define KWIN 7
#define PADV 3

typedef short  short8 __attribute__((ext_vector_type(8)));
typedef float  f32x4  __attribute__((ext_vector_type(4)));

__device__ inline void split_bf16(float f, unsigned short& hi, unsigned short& lo) {
    union { float f; unsigned u; } a; a.f = f;
    unsigned r = a.u + 0x7FFF + ((a.u >> 16) & 1);     // RNE to bf16
    hi = (unsigned short)(r >> 16);
    union { unsigned u; float f; } hf; hf.u = (unsigned)hi << 16;
    union { float f; unsigned u; } b; b.f = f - hf.f;
    unsigned r2 = b.u + 0x7FFF + ((b.u >> 16) & 1);
    lo = (unsigned short)(r2 >> 16);
}

// ---------- convert+transpose x: [B][C][S] f32 -> Xt_hi/Xt_lo [B][S][C] bf16 ----------
__global__ __launch_bounds__(256) void convert_x(
    const float* __restrict__ x,
    unsigned short* __restrict__ xt_hi,
    unsigned short* __restrict__ xt_lo)
{
    __shared__ float tile[64][65];
    const int t  = threadIdx.x;
    const int s0 = blockIdx.x * 64;
    const int c0 = blockIdx.y * 64;
    const int b  = blockIdx.z;
    const float* xb = x + ((size_t)b * CIN + c0) * S + s0;
#pragma unroll
    for (int j = 0; j < 4; ++j) {
        const int i   = t + j * 256;     // 0..1023 float4s
        const int row = i >> 4;          // c_local
        const int cq  = i & 15;          // float4 along s
        float4 v = *(const float4*)(xb + (size_t)row * S + cq * 4);
        tile[row][cq * 4 + 0] = v.x;
        tile[row][cq * 4 + 1] = v.y;
        tile[row][cq * 4 + 2] = v.z;
        tile[row][cq * 4 + 3] = v.w;
    }
    __syncthreads();
#pragma unroll
    for (int j = 0; j < 4; ++j) {
        const int i    = t + j * 256;
        const int srow = i >> 4;         // s_local
        const int cq   = i & 15;         // 4-c chunk
        ushort4 h, l;
        split_bf16(tile[cq * 4 + 0][srow], h.x, l.x);
        split_bf16(tile[cq * 4 + 1][srow], h.y, l.y);
        split_bf16(tile[cq * 4 + 2][srow], h.z, l.z);
        split_bf16(tile[cq * 4 + 3][srow], h.w, l.w);
        const size_t off = ((size_t)b * S + s0 + srow) * CIN + c0 + cq * 4;
        *(ushort4*)(xt_hi + off) = h;
        *(ushort4*)(xt_lo + off) = l;
    }
}

// ---------- convert weights: wq/wk/wv [O][C] f32 -> wt_hi/wt_lo [3][O][C] bf16 ----------
__global__ __launch_bounds__(256) void convert_w(
    const float* __restrict__ wq, const float* __restrict__ wk, const float* __restrict__ wv,
    unsigned short* __restrict__ wt_hi, unsigned short* __restrict__ wt_lo)
{
    const int t = threadIdx.x;
#pragma unroll
    for (int j = 0; j < 2; ++j) {
        const int e  = blockIdx.x * 2048 + j * 1024 + t * 4;   // elem idx in [0, 3*65536)
        const int mi = e >> 16;
        const int of = e & 65535;
        const float* ws = (mi == 0) ? wq : (mi == 1 ? wk : wv);
        float4 v = *(const float4*)(ws + of);
        ushort4 h, l;
        split_bf16(v.x, h.x, l.x);
        split_bf16(v.y, h.y, l.y);
        split_bf16(v.z, h.z, l.z);
        split_bf16(v.w, h.w, l.w);
        *(ushort4*)(wt_hi + e) = h;
        *(ushort4*)(wt_lo + e) = l;
    }
}

// ---------- MFMA QKV: D[s][o] = sum_c Xt[s][c] * W[o][c], hi/lo split ----------
// 256 thr = 4 waves; block tile 64(s) x 256(o); wave = 64(s) x 64(o); K=256 fully unrolled.
// A-frag: lane&15 -> s row, (lane>>4)*8 -> consecutive c (16B load from Xt).
// B-frag: lane&15 -> o row, (lane>>4)*8 -> consecutive c (16B load from W bf16).
// D: col(o)=lane&15, row(s)=(lane>>4)*4+reg  ->  float4 store along s.
__global__ __launch_bounds__(256) void qkv_mfma(
    const unsigned short* __restrict__ xt_hi,
    const unsigned short* __restrict__ xt_lo,
    const unsigned short* __restrict__ wt_hi,
    const unsigned short* __restrict__ wt_lo,
    float* __restrict__ qout, float* __restrict__ kout, float* __restrict__ vout)
{
    const int t    = threadIdx.x;
    const int lane = t & 63;
    const int wid  = t >> 6;
    const int r16  = lane & 15;
    const int kq   = lane >> 4;
    const int s0   = blockIdx.x * 64;
    const int bm   = blockIdx.y;         // b*3 + m
    const int b    = bm / 3, m = bm % 3;
    float* outp = ((m == 0) ? qout : (m == 1 ? kout : vout)) + (size_t)b * COUT * S;

    const size_t abase = ((size_t)b * S + s0 + r16) * CIN + kq * 8;
    const size_t bbase = ((size_t)(m * COUT + wid * 64 + r16)) * CIN + kq * 8;

    f32x4 acc[4][4] = {};
#pragma unroll
    for (int kb = 0; kb < 8; ++kb) {
        short8 ah[4], al[4], bh[4], bl[4];
#pragma unroll
        for (int i = 0; i < 4; ++i) {
            const size_t ao = abase + (size_t)i * 16 * CIN + kb * 32;
            ah[i] = *(const short8*)(xt_hi + ao);
            al[i] = *(const short8*)(xt_lo + ao);
            const size_t bo = bbase + (size_t)i * 16 * CIN + kb * 32;
            bh[i] = *(const short8*)(wt_hi + bo);
            bl[i] = *(const short8*)(wt_lo + bo);
        }
#pragma unroll
        for (int i = 0; i < 4; ++i)
#pragma unroll
            for (int j = 0; j < 4; ++j) {
                acc[i][j] = __builtin_amdgcn_mfma_f32_16x16x32_bf16(ah[i], bh[j], acc[i][j], 0, 0, 0);
                acc[i][j] = __builtin_amdgcn_mfma_f32_16x16x32_bf16(al[i], bh[j], acc[i][j], 0, 0, 0);
                acc[i][j] = __builtin_amdgcn_mfma_f32_16x16x32_bf16(ah[i], bl[j], acc[i][j], 0, 0, 0);
            }
    }
#pragma unroll
    for (int i = 0; i < 4; ++i)      // ms (s subtile)
#pragma unroll
        for (int j = 0; j < 4; ++j) { // ns (o subtile)
            const int o = wid * 64 + j * 16 + r16;
            const int s = s0 + i * 16 + kq * 4;
            float4 r = make_float4(acc[i][j][0], acc[i][j][1], acc[i][j][2], acc[i][j][3]);
            *(float4*)(outp + (size_t)o * S + s) = r;
        }
}

// ---------------- Phase 2: windowed per-channel softmax-attention (unchanged) ----------------
__global__ __launch_bounds__(192) void attn_win(
    const float* __restrict__ qmap,
    const float* __restrict__ kmap,
    const float* __restrict__ vmap,
    const float* __restrict__ rel_h,
    const float* __restrict__ rel_w,
    float* __restrict__ out)
{
    __shared__ float Ks[10][56];
    __shared__ float Vs[10][56];
    const int t  = threadIdx.x;
    const int h0 = blockIdx.x * 4;
    const int bo = blockIdx.y;
    const int o  = bo & 255;
    const float* kp = kmap + (size_t)bo * S;
    const float* vp = vmap + (size_t)bo * S;

#pragma unroll
    for (int i = t; i < 560; i += 192) {
        const int row = i / 56, col = i - row * 56;
        const int hh = h0 - 3 + row, ww = col - 3;
        const bool ok = ((unsigned)hh < (unsigned)HH) && ((unsigned)ww < (unsigned)WW);
        Ks[row][col] = ok ? kp[hh * WW + ww] : 0.f;
        Vs[row][col] = ok ? vp[hh * WW + ww] : 0.f;
    }

    const int w = t % 48;
    const int r = t / 48;
    const int h = h0 + r;
    const float q = qmap[(size_t)bo * S + h * WW + w];
    const bool ish = (o < 128);
    const float* rp = ish ? (rel_h + o * 7) : (rel_w + (o - 128) * 7);
    float qr[7];
#pragma unroll
    for (int i = 0; i < 7; ++i) qr[i] = q * rp[i];

    __syncthreads();

    float l[2] = {0.f, 0.f}, a[2] = {0.f, 0.f};
    if (ish) {
#pragma unroll
        for (int kh = 0; kh < KWIN; ++kh) {
            const float bb = qr[kh];
            const float* kr = &Ks[r + kh][w];
            const float* vr = &Vs[r + kh][w];
#pragma unroll
            for (int kw = 0; kw < KWIN; ++kw) {
                const float p = __expf(fmaf(q, kr[kw], bb));
                l[kw & 1] += p;
                a[kw & 1] = fmaf(p, vr[kw], a[kw & 1]);
            }
        }
    } else {
#pragma unroll
        for (int kh = 0; kh < KWIN; ++kh) {
            const float* kr = &Ks[r + kh][w];
            const float* vr = &Vs[r + kh][w];
#pragma unroll
            for (int kw = 0; kw < KWIN; ++kw) {
                const float p = __expf(fmaf(q, kr[kw], qr[kw]));
                l[kw & 1] += p;
                a[kw & 1] = fmaf(p, vr[kw], a[kw & 1]);
            }
        }
    }
    out[(size_t)bo * S + h * WW + w] = (a[0] + a[1]) / (l[0] + l[1]);
}

extern "C" void kernel_launch(void* const* d_in, const int* in_sizes, int n_in,
                              void* d_out, int out_size, void* d_ws, size_t ws_size,
                              hipStream_t stream) {
    const float* x     = (const float*)d_in[0];
    const float* wq    = (const float*)d_in[1];
    const float* wk    = (const float*)d_in[2];
    const float* wv    = (const float*)d_in[3];
    const float* rel_h = (const float*)d_in[4];
    const float* rel_w = (const float*)d_in[5];
    float* out  = (float*)d_out;

    float* kbuf = (float*)d_ws;                             // [B][O][S] f32
    float* vbuf = kbuf + (size_t)BSZ * COUT * S;            // [B][O][S] f32
    unsigned short* xt_hi = (unsigned short*)(vbuf + (size_t)BSZ * COUT * S);
    unsigned short* xt_lo = xt_hi + (size_t)BSZ * S * CIN;  // [B][S][C] bf16
    unsigned short* wt_hi = xt_lo + (size_t)BSZ * S * CIN;  // [3][O][C] bf16
    unsigned short* wt_lo = wt_hi + (size_t)3 * COUT * CIN;

    dim3 gx(S / 64, CIN / 64, BSZ);                         // (36,4,2)
    convert_x<<<gx, 256, 0, stream>>>(x, xt_hi, xt_lo);
    convert_w<<<96, 256, 0, stream>>>(wq, wk, wv, wt_hi, wt_lo);

    dim3 gg(S / 64, BSZ * 3);                               // (36,6)
    qkv_mfma<<<gg, 256, 0, stream>>>(xt_hi, xt_lo, wt_hi, wt_lo, out, kbuf, vbuf);

    dim3 g2(HH / 4, BSZ * COUT);                            // (12,512)
    attn_win<<<g2, 192, 0, stream>>>(out, kbuf, vbuf, rel_h, rel_w, out);
}

// Round 4
// 49.435 us; speedup vs baseline: 1.6436x; 1.0372x over previous
//
#include <hip/hip_runtime.h>

#define CIN  256
#define COUT 256
#define BSZ  2
#define HH   48
#define WW   48
#define S    (HH * WW)   // 2304
#define KWIN 7
#define PADV 3

typedef short  short8 __attribute__((ext_vector_type(8)));
typedef float  f32x4  __attribute__((ext_vector_type(4)));

__device__ inline unsigned rne_hi(unsigned u) {
    return (u + 0x7FFFu + ((u >> 16) & 1u)) & 0xFFFF0000u;
}

__device__ inline void split_bf16(float f, unsigned short& hi, unsigned short& lo) {
    union { float f; unsigned u; } a; a.f = f;
    unsigned r = a.u + 0x7FFF + ((a.u >> 16) & 1);     // RNE to bf16
    hi = (unsigned short)(r >> 16);
    union { unsigned u; float f; } hf; hf.u = (unsigned)hi << 16;
    union { float f; unsigned u; } b; b.f = f - hf.f;
    unsigned r2 = b.u + 0x7FFF + ((b.u >> 16) & 1);
    lo = (unsigned short)(r2 >> 16);
}

// ---------- convert weights: wq/wk/wv [O][C] f32 -> wt_hi/wt_lo [3][O][C] bf16 ----------
__global__ __launch_bounds__(256) void convert_w(
    const float* __restrict__ wq, const float* __restrict__ wk, const float* __restrict__ wv,
    unsigned short* __restrict__ wt_hi, unsigned short* __restrict__ wt_lo)
{
    const int t = threadIdx.x;
#pragma unroll
    for (int j = 0; j < 2; ++j) {
        const int e  = blockIdx.x * 2048 + j * 1024 + t * 4;   // elem idx in [0, 3*65536)
        const int mi = e >> 16;
        const int of = e & 65535;
        const float* ws = (mi == 0) ? wq : (mi == 1 ? wk : wv);
        float4 v = *(const float4*)(ws + of);
        ushort4 h, l;
        split_bf16(v.x, h.x, l.x);
        split_bf16(v.y, h.y, l.y);
        split_bf16(v.z, h.z, l.z);
        split_bf16(v.w, h.w, l.w);
        *(ushort4*)(wt_hi + e) = h;
        *(ushort4*)(wt_lo + e) = l;
    }
}

// ---------- MFMA QKV: D[s][o] = sum_c X[c][s] * W[o][c], hi/lo split, fused convert ----------
// 256 thr = 4 waves; block tile 64(s) x 256(o) for one (b,m); wave = 64(s) x 64(o).
// A loaded directly from f32 x (coalesced dwords, c-strided per lane) and split in-register.
// B loaded from pre-split bf16 weights.
// D: col(o)=lane&15, row(s)=(lane>>4)*4+reg  ->  float4 store along s.
__global__ __launch_bounds__(256) void qkv_mfma(
    const float* __restrict__ x,              // [B][C][S]
    const unsigned short* __restrict__ wt_hi, // [3][O][C]
    const unsigned short* __restrict__ wt_lo,
    float* __restrict__ qout, float* __restrict__ kout, float* __restrict__ vout)
{
    const int t    = threadIdx.x;
    const int lane = t & 63;
    const int wid  = t >> 6;
    const int r16  = lane & 15;
    const int kq   = lane >> 4;
    const int s0   = blockIdx.x * 64;
    const int bm   = blockIdx.y;         // b*3 + m
    const int b    = bm / 3, m = bm % 3;
    float* outp = ((m == 0) ? qout : (m == 1 ? kout : vout)) + (size_t)b * COUT * S;

    const float* xb = x + (size_t)b * CIN * S;
    const size_t bbase = ((size_t)(m * COUT + wid * 64 + r16)) * CIN + kq * 8;

    f32x4 acc[4][4] = {};
#pragma unroll 2
    for (int kb = 0; kb < 8; ++kb) {
        short8 ah[4], al[4], bh[4], bl[4];
#pragma unroll
        for (int i = 0; i < 4; ++i) {
            // A fragment: s = s0 + i*16 + r16 ; c = kb*32 + kq*8 + e
            const float* pa = xb + (size_t)(kb * 32 + kq * 8) * S + (s0 + i * 16 + r16);
            float f[8];
#pragma unroll
            for (int e = 0; e < 8; ++e) f[e] = pa[(size_t)e * S];
            union { short8 v; unsigned u[4]; } Hh, Ll;
#pragma unroll
            for (int p = 0; p < 4; ++p) {
                const float a = f[2 * p], c = f[2 * p + 1];
                const unsigned ua = __float_as_uint(a), uc = __float_as_uint(c);
                const unsigned ha = rne_hi(ua), hc = rne_hi(uc);
                Hh.u[p] = (ha >> 16) | hc;
                const float ra = a - __uint_as_float(ha);
                const float rc = c - __uint_as_float(hc);
                Ll.u[p] = (__float_as_uint(ra) >> 16) | (__float_as_uint(rc) & 0xFFFF0000u);
            }
            ah[i] = Hh.v; al[i] = Ll.v;
            // B fragment: o = wid*64 + i*16 + r16 ; c = kb*32 + kq*8 + e
            const size_t bo = bbase + (size_t)i * 16 * CIN + kb * 32;
            bh[i] = *(const short8*)(wt_hi + bo);
            bl[i] = *(const short8*)(wt_lo + bo);
        }
#pragma unroll
        for (int i = 0; i < 4; ++i)
#pragma unroll
            for (int j = 0; j < 4; ++j) {
                acc[i][j] = __builtin_amdgcn_mfma_f32_16x16x32_bf16(ah[i], bh[j], acc[i][j], 0, 0, 0);
                acc[i][j] = __builtin_amdgcn_mfma_f32_16x16x32_bf16(al[i], bh[j], acc[i][j], 0, 0, 0);
                acc[i][j] = __builtin_amdgcn_mfma_f32_16x16x32_bf16(ah[i], bl[j], acc[i][j], 0, 0, 0);
            }
    }
#pragma unroll
    for (int i = 0; i < 4; ++i)      // s subtile
#pragma unroll
        for (int j = 0; j < 4; ++j) { // o subtile
            const int o = wid * 64 + j * 16 + r16;
            const int s = s0 + i * 16 + kq * 4;
            float4 r = make_float4(acc[i][j][0], acc[i][j][1], acc[i][j][2], acc[i][j][3]);
            *(float4*)(outp + (size_t)o * S + s) = r;
        }
}

// ---------------- Phase 2: windowed per-channel softmax-attention ----------------
// Block = 8 rows x 48 cols of one (b,o) plane, 384 threads (6 waves).
// Zero-padded LDS halo (14x56) for k,v — matches reference semantics exactly
// (bias-only scores at padded positions, v=0 there).
__global__ __launch_bounds__(384) void attn_win(
    const float* __restrict__ qmap,   // [B*O][S] (lives in d_out)
    const float* __restrict__ kmap,
    const float* __restrict__ vmap,
    const float* __restrict__ rel_h,
    const float* __restrict__ rel_w,
    float* __restrict__ out)          // same buffer as qmap
{
    __shared__ float Ks[14][56];
    __shared__ float Vs[14][56];
    const int t  = threadIdx.x;
    const int h0 = blockIdx.x * 8;
    const int bo = blockIdx.y;
    const int o  = bo & 255;
    const float* kp = kmap + (size_t)bo * S;
    const float* vp = vmap + (size_t)bo * S;

#pragma unroll
    for (int i = t; i < 784; i += 384) {
        const int row = i / 56, col = i - row * 56;
        const int hh = h0 - 3 + row, ww = col - 3;
        const bool ok = ((unsigned)hh < (unsigned)HH) && ((unsigned)ww < (unsigned)WW);
        Ks[row][col] = ok ? kp[hh * WW + ww] : 0.f;
        Vs[row][col] = ok ? vp[hh * WW + ww] : 0.f;
    }

    const int w = t % 48;
    const int r = t / 48;            // 0..7
    const int h = h0 + r;
    const float q = qmap[(size_t)bo * S + h * WW + w];
    const bool ish = (o < 128);
    const float* rp = ish ? (rel_h + o * 7) : (rel_w + (o - 128) * 7);
    float qr[7];
#pragma unroll
    for (int i = 0; i < 7; ++i) qr[i] = q * rp[i];

    __syncthreads();

    float l[2] = {0.f, 0.f}, a[2] = {0.f, 0.f};
    if (ish) {
#pragma unroll
        for (int kh = 0; kh < KWIN; ++kh) {
            const float bb = qr[kh];
            const float* kr = &Ks[r + kh][w];
            const float* vr = &Vs[r + kh][w];
#pragma unroll
            for (int kw = 0; kw < KWIN; ++kw) {
                const float p = __expf(fmaf(q, kr[kw], bb));
                l[kw & 1] += p;
                a[kw & 1] = fmaf(p, vr[kw], a[kw & 1]);
            }
        }
    } else {
#pragma unroll
        for (int kh = 0; kh < KWIN; ++kh) {
            const float* kr = &Ks[r + kh][w];
            const float* vr = &Vs[r + kh][w];
#pragma unroll
            for (int kw = 0; kw < KWIN; ++kw) {
                const float p = __expf(fmaf(q, kr[kw], qr[kw]));
                l[kw & 1] += p;
                a[kw & 1] = fmaf(p, vr[kw], a[kw & 1]);
            }
        }
    }
    out[(size_t)bo * S + h * WW + w] = (a[0] + a[1]) / (l[0] + l[1]);
}

extern "C" void kernel_launch(void* const* d_in, const int* in_sizes, int n_in,
                              void* d_out, int out_size, void* d_ws, size_t ws_size,
                              hipStream_t stream) {
    const float* x     = (const float*)d_in[0];
    const float* wq    = (const float*)d_in[1];
    const float* wk    = (const float*)d_in[2];
    const float* wv    = (const float*)d_in[3];
    const float* rel_h = (const float*)d_in[4];
    const float* rel_w = (const float*)d_in[5];
    float* out  = (float*)d_out;

    float* kbuf = (float*)d_ws;                             // [B][O][S] f32
    float* vbuf = kbuf + (size_t)BSZ * COUT * S;            // [B][O][S] f32
    unsigned short* wt_hi = (unsigned short*)(vbuf + (size_t)BSZ * COUT * S);
    unsigned short* wt_lo = wt_hi + (size_t)3 * COUT * CIN; // [3][O][C] bf16

    convert_w<<<96, 256, 0, stream>>>(wq, wk, wv, wt_hi, wt_lo);

    dim3 gg(S / 64, BSZ * 3);                               // (36,6)
    qkv_mfma<<<gg, 256, 0, stream>>>(x, wt_hi, wt_lo, out, kbuf, vbuf);

    dim3 g2(HH / 8, BSZ * COUT);                            // (6,512)
    attn_win<<<g2, 384, 0, stream>>>(out, kbuf, vbuf, rel_h, rel_w, out);
}

// Round 5
// 47.518 us; speedup vs baseline: 1.7100x; 1.0404x over previous
//
#include <hip/hip_runtime.h>

#define CIN  256
#define COUT 256
#define BSZ  2
#define HH   48
#define WW   48
#define S    (HH * WW)   // 2304
#define KWIN 7
#define PADV 3

typedef short  short8 __attribute__((ext_vector_type(8)));
typedef float  f32x4  __attribute__((ext_vector_type(4)));

__device__ inline unsigned rne_hi(unsigned u) {
    return (u + 0x7FFFu + ((u >> 16) & 1u)) & 0xFFFF0000u;
}

__device__ inline void split_bf16(float f, unsigned short& hi, unsigned short& lo) {
    union { float f; unsigned u; } a; a.f = f;
    unsigned r = a.u + 0x7FFF + ((a.u >> 16) & 1);     // RNE to bf16
    hi = (unsigned short)(r >> 16);
    union { unsigned u; float f; } hf; hf.u = (unsigned)hi << 16;
    union { float f; unsigned u; } b; b.f = f - hf.f;
    unsigned r2 = b.u + 0x7FFF + ((b.u >> 16) & 1);
    lo = (unsigned short)(r2 >> 16);
}

// ---------- convert weights: wq/wk/wv [O][C] f32 -> wt_hi/wt_lo [3][O][C] bf16 ----------
__global__ __launch_bounds__(256) void convert_w(
    const float* __restrict__ wq, const float* __restrict__ wk, const float* __restrict__ wv,
    unsigned short* __restrict__ wt_hi, unsigned short* __restrict__ wt_lo)
{
    const int t = threadIdx.x;
#pragma unroll
    for (int j = 0; j < 2; ++j) {
        const int e  = blockIdx.x * 2048 + j * 1024 + t * 4;
        const int mi = e >> 16;
        const int of = e & 65535;
        const float* ws = (mi == 0) ? wq : (mi == 1 ? wk : wv);
        float4 v = *(const float4*)(ws + of);
        ushort4 h, l;
        split_bf16(v.x, h.x, l.x);
        split_bf16(v.y, h.y, l.y);
        split_bf16(v.z, h.z, l.z);
        split_bf16(v.w, h.w, l.w);
        *(ushort4*)(wt_hi + e) = h;
        *(ushort4*)(wt_lo + e) = l;
    }
}

// ---------- MFMA QKV (unchanged from round 4) ----------
__global__ __launch_bounds__(256) void qkv_mfma(
    const float* __restrict__ x,              // [B][C][S]
    const unsigned short* __restrict__ wt_hi, // [3][O][C]
    const unsigned short* __restrict__ wt_lo,
    float* __restrict__ qout, float* __restrict__ kout, float* __restrict__ vout)
{
    const int t    = threadIdx.x;
    const int lane = t & 63;
    const int wid  = t >> 6;
    const int r16  = lane & 15;
    const int kq   = lane >> 4;
    const int s0   = blockIdx.x * 64;
    const int bm   = blockIdx.y;         // b*3 + m
    const int b    = bm / 3, m = bm % 3;
    float* outp = ((m == 0) ? qout : (m == 1 ? kout : vout)) + (size_t)b * COUT * S;

    const float* xb = x + (size_t)b * CIN * S;
    const size_t bbase = ((size_t)(m * COUT + wid * 64 + r16)) * CIN + kq * 8;

    f32x4 acc[4][4] = {};
#pragma unroll 2
    for (int kb = 0; kb < 8; ++kb) {
        short8 ah[4], al[4], bh[4], bl[4];
#pragma unroll
        for (int i = 0; i < 4; ++i) {
            const float* pa = xb + (size_t)(kb * 32 + kq * 8) * S + (s0 + i * 16 + r16);
            float f[8];
#pragma unroll
            for (int e = 0; e < 8; ++e) f[e] = pa[(size_t)e * S];
            union { short8 v; unsigned u[4]; } Hh, Ll;
#pragma unroll
            for (int p = 0; p < 4; ++p) {
                const float a = f[2 * p], c = f[2 * p + 1];
                const unsigned ha = rne_hi(__float_as_uint(a)), hc = rne_hi(__float_as_uint(c));
                Hh.u[p] = (ha >> 16) | hc;
                const float ra = a - __uint_as_float(ha);
                const float rc = c - __uint_as_float(hc);
                Ll.u[p] = (__float_as_uint(ra) >> 16) | (__float_as_uint(rc) & 0xFFFF0000u);
            }
            ah[i] = Hh.v; al[i] = Ll.v;
            const size_t bo = bbase + (size_t)i * 16 * CIN + kb * 32;
            bh[i] = *(const short8*)(wt_hi + bo);
            bl[i] = *(const short8*)(wt_lo + bo);
        }
#pragma unroll
        for (int i = 0; i < 4; ++i)
#pragma unroll
            for (int j = 0; j < 4; ++j) {
                acc[i][j] = __builtin_amdgcn_mfma_f32_16x16x32_bf16(ah[i], bh[j], acc[i][j], 0, 0, 0);
                acc[i][j] = __builtin_amdgcn_mfma_f32_16x16x32_bf16(al[i], bh[j], acc[i][j], 0, 0, 0);
                acc[i][j] = __builtin_amdgcn_mfma_f32_16x16x32_bf16(ah[i], bl[j], acc[i][j], 0, 0, 0);
            }
    }
#pragma unroll
    for (int i = 0; i < 4; ++i)
#pragma unroll
        for (int j = 0; j < 4; ++j) {
            const int o = wid * 64 + j * 16 + r16;
            const int s = s0 + i * 16 + kq * 4;
            float4 r = make_float4(acc[i][j][0], acc[i][j][1], acc[i][j][2], acc[i][j][3]);
            *(float4*)(outp + (size_t)o * S + s) = r;
        }
}

// ---------------- Phase 2: windowed softmax-attention, 4 outputs/thread ----------------
// Block = 16 h-rows; thread -> 4 consecutive w (w0 % 4 == 0). Per kh, each thread reads
// 12 K-floats + 12 V-floats as 3+3 aligned ds_read_b128 covering all 4 windows
// (was 98 scalar b32 per single output). LDS rows padded to 60 floats (240 B: keeps
// 16 B alignment, spreads banks). exp2 with log2e prefolded into q.
__global__ __launch_bounds__(192) void attn_win(
    const float* __restrict__ qmap,   // [B*O][S] (lives in d_out)
    const float* __restrict__ kmap,
    const float* __restrict__ vmap,
    const float* __restrict__ rel_h,
    const float* __restrict__ rel_w,
    float* __restrict__ out)          // same buffer as qmap
{
    __shared__ __align__(16) float Ks[22][60];
    __shared__ __align__(16) float Vs[22][60];
    const int t  = threadIdx.x;
    const int h0 = blockIdx.x * 16;
    const int bo = blockIdx.y;
    const int o  = bo & 255;
    const float* kp = kmap + (size_t)bo * S;
    const float* vp = vmap + (size_t)bo * S;

    // stage rows h0-3..h0+18, cols -3..52 (col = w+3, width 56 used of 60)
    for (int i = t; i < 22 * 56; i += 192) {
        const int row = i / 56, col = i - row * 56;
        const int hh = h0 - 3 + row, ww = col - 3;
        const bool ok = ((unsigned)hh < (unsigned)HH) && ((unsigned)ww < (unsigned)WW);
        Ks[row][col] = ok ? kp[hh * WW + ww] : 0.f;
        Vs[row][col] = ok ? vp[hh * WW + ww] : 0.f;
    }

    const int w0 = (t % 12) * 4;     // output cols w0..w0+3
    const int r  = t / 12;           // 0..15
    const int h  = h0 + r;
    const float4 q4 = *(const float4*)(qmap + (size_t)bo * S + h * WW + w0);
    const float qe[4] = {q4.x * 1.44269504088896340736f,
                         q4.y * 1.44269504088896340736f,
                         q4.z * 1.44269504088896340736f,
                         q4.w * 1.44269504088896340736f};
    const bool ish = (o < 128);
    const float* rp = ish ? (rel_h + o * 7) : (rel_w + (o - 128) * 7);
    float rel[7];
#pragma unroll
    for (int i = 0; i < 7; ++i) rel[i] = rp[i];

    __syncthreads();

    float l[4] = {0.f, 0.f, 0.f, 0.f}, a[4] = {0.f, 0.f, 0.f, 0.f};
#pragma unroll
    for (int kh = 0; kh < KWIN; ++kh) {
        const int rr = r + kh;
        const float4 ka = *(const float4*)&Ks[rr][w0];
        const float4 kb = *(const float4*)&Ks[rr][w0 + 4];
        const float4 kc = *(const float4*)&Ks[rr][w0 + 8];
        const float4 va = *(const float4*)&Vs[rr][w0];
        const float4 vb = *(const float4*)&Vs[rr][w0 + 4];
        const float4 vc = *(const float4*)&Vs[rr][w0 + 8];
        const float ks[12] = {ka.x, ka.y, ka.z, ka.w, kb.x, kb.y, kb.z, kb.w, kc.x, kc.y, kc.z, kc.w};
        const float vs[12] = {va.x, va.y, va.z, va.w, vb.x, vb.y, vb.z, vb.w, vc.x, vc.y, vc.z, vc.w};
        if (ish) {
#pragma unroll
            for (int d = 0; d < 4; ++d) {
                const float bias = qe[d] * rel[kh];
#pragma unroll
                for (int kw = 0; kw < KWIN; ++kw) {
                    const float p = __builtin_amdgcn_exp2f(fmaf(qe[d], ks[d + kw], bias));
                    l[d] += p;
                    a[d] = fmaf(p, vs[d + kw], a[d]);
                }
            }
        } else {
#pragma unroll
            for (int d = 0; d < 4; ++d) {
#pragma unroll
                for (int kw = 0; kw < KWIN; ++kw) {
                    const float p = __builtin_amdgcn_exp2f(fmaf(qe[d], ks[d + kw], qe[d] * rel[kw]));
                    l[d] += p;
                    a[d] = fmaf(p, vs[d + kw], a[d]);
                }
            }
        }
    }
    float4 ov = make_float4(a[0] / l[0], a[1] / l[1], a[2] / l[2], a[3] / l[3]);
    *(float4*)(out + (size_t)bo * S + h * WW + w0) = ov;
}

extern "C" void kernel_launch(void* const* d_in, const int* in_sizes, int n_in,
                              void* d_out, int out_size, void* d_ws, size_t ws_size,
                              hipStream_t stream) {
    const float* x     = (const float*)d_in[0];
    const float* wq    = (const float*)d_in[1];
    const float* wk    = (const float*)d_in[2];
    const float* wv    = (const float*)d_in[3];
    const float* rel_h = (const float*)d_in[4];
    const float* rel_w = (const float*)d_in[5];
    float* out  = (float*)d_out;

    float* kbuf = (float*)d_ws;                             // [B][O][S] f32
    float* vbuf = kbuf + (size_t)BSZ * COUT * S;            // [B][O][S] f32
    unsigned short* wt_hi = (unsigned short*)(vbuf + (size_t)BSZ * COUT * S);
    unsigned short* wt_lo = wt_hi + (size_t)3 * COUT * CIN; // [3][O][C] bf16

    convert_w<<<96, 256, 0, stream>>>(wq, wk, wv, wt_hi, wt_lo);

    dim3 gg(S / 64, BSZ * 3);                               // (36,6)
    qkv_mfma<<<gg, 256, 0, stream>>>(x, wt_hi, wt_lo, out, kbuf, vbuf);

    dim3 g2(HH / 16, BSZ * COUT);                           // (3,512)
    attn_win<<<g2, 192, 0, stream>>>(out, kbuf, vbuf, rel_h, rel_w, out);
}

// Round 6
// 42.563 us; speedup vs baseline: 1.9090x; 1.1164x over previous
//
#include <hip/hip_runtime.h>

#define CIN  256
#define COUT 256
#define BSZ  2
#define HH   48
#define WW   48
#define S    (HH * WW)   // 2304
#define KWIN 7
#define PADV 3

typedef short  short8 __attribute__((ext_vector_type(8)));
typedef float  f32x4  __attribute__((ext_vector_type(4)));

__device__ inline unsigned rne_hi(unsigned u) {
    return (u + 0x7FFFu + ((u >> 16) & 1u)) & 0xFFFF0000u;
}

// split 8 consecutive floats into packed bf16 hi (RNE) + lo (truncated residual)
__device__ inline void split8(const float f[8], short8& hv, short8& lv) {
    union { short8 v; unsigned u[4]; } Hh, Ll;
#pragma unroll
    for (int p = 0; p < 4; ++p) {
        const float a = f[2 * p], c = f[2 * p + 1];
        const unsigned ha = rne_hi(__float_as_uint(a)), hc = rne_hi(__float_as_uint(c));
        Hh.u[p] = (ha >> 16) | hc;
        const float ra = a - __uint_as_float(ha);
        const float rc = c - __uint_as_float(hc);
        Ll.u[p] = (__float_as_uint(ra) >> 16) | (__float_as_uint(rc) & 0xFFFF0000u);
    }
    hv = Hh.v; lv = Ll.v;
}

// ---------- MFMA QKV: D[s][o] = sum_c X[c][s] * W[o][c], hi/lo split, fully fused ----------
// Block = 64(s) x 128(o) for one (b,m); 4 waves, wave = 64(s) x 32(o); K=256.
// Both operands converted f32 -> bf16 hi/lo in-register (3-MFMA compensated product).
// D: col-dim(o)=lane&15, row-dim(s)=(lane>>4)*4+reg -> float4 store along s.
__global__ __launch_bounds__(256) void qkv_mfma(
    const float* __restrict__ x,              // [B][C][S]
    const float* __restrict__ wq, const float* __restrict__ wk, const float* __restrict__ wv,
    float* __restrict__ qout, float* __restrict__ kout, float* __restrict__ vout)
{
    const int t    = threadIdx.x;
    const int lane = t & 63;
    const int wid  = t >> 6;
    const int r16  = lane & 15;
    const int kq   = lane >> 4;
    const int s0   = blockIdx.x * 64;
    const int o0   = blockIdx.y * 128 + wid * 32;
    const int bm   = blockIdx.z;         // b*3 + m
    const int b    = bm / 3, m = bm % 3;
    const float* wmat = (m == 0) ? wq : (m == 1 ? wk : wv);
    float* outp = ((m == 0) ? qout : (m == 1 ? kout : vout)) + (size_t)b * COUT * S;

    const float* xb = x + (size_t)b * CIN * S;

    f32x4 acc[4][2] = {};
#pragma unroll 2
    for (int kb = 0; kb < 8; ++kb) {
        short8 ah[4], al[4], bh[2], bl[2];
#pragma unroll
        for (int i = 0; i < 4; ++i) {
            // A fragment: s = s0 + i*16 + r16 ; c = kb*32 + kq*8 + e
            const float* pa = xb + (size_t)(kb * 32 + kq * 8) * S + (s0 + i * 16 + r16);
            float f[8];
#pragma unroll
            for (int e = 0; e < 8; ++e) f[e] = pa[(size_t)e * S];
            split8(f, ah[i], al[i]);
        }
#pragma unroll
        for (int j = 0; j < 2; ++j) {
            // B fragment: o = o0 + j*16 + r16 ; c = kb*32 + kq*8 + e
            const float* pw = wmat + (size_t)(o0 + j * 16 + r16) * CIN + kb * 32 + kq * 8;
            float4 wa = *(const float4*)pw;
            float4 wb = *(const float4*)(pw + 4);
            float f[8] = {wa.x, wa.y, wa.z, wa.w, wb.x, wb.y, wb.z, wb.w};
            split8(f, bh[j], bl[j]);
        }
#pragma unroll
        for (int i = 0; i < 4; ++i)
#pragma unroll
            for (int j = 0; j < 2; ++j) {
                acc[i][j] = __builtin_amdgcn_mfma_f32_16x16x32_bf16(ah[i], bh[j], acc[i][j], 0, 0, 0);
                acc[i][j] = __builtin_amdgcn_mfma_f32_16x16x32_bf16(al[i], bh[j], acc[i][j], 0, 0, 0);
                acc[i][j] = __builtin_amdgcn_mfma_f32_16x16x32_bf16(ah[i], bl[j], acc[i][j], 0, 0, 0);
            }
    }
#pragma unroll
    for (int i = 0; i < 4; ++i)      // s subtile
#pragma unroll
        for (int j = 0; j < 2; ++j) { // o subtile
            const int o = o0 + j * 16 + r16;
            const int s = s0 + i * 16 + kq * 4;
            float4 r = make_float4(acc[i][j][0], acc[i][j][1], acc[i][j][2], acc[i][j][3]);
            *(float4*)(outp + (size_t)o * S + s) = r;
        }
}

// ---------------- Phase 2: windowed softmax-attention, 4 outputs/thread ----------------
// Block = 16 h-rows; thread -> 4 consecutive w. Per kh: 3+3 aligned ds_read_b128
// cover all 4 windows. Zero-padded halo matches reference semantics exactly.
// exp2 with log2e prefolded into q.
__global__ __launch_bounds__(192) void attn_win(
    const float* __restrict__ qmap,   // [B*O][S] (lives in d_out)
    const float* __restrict__ kmap,
    const float* __restrict__ vmap,
    const float* __restrict__ rel_h,
    const float* __restrict__ rel_w,
    float* __restrict__ out)          // same buffer as qmap
{
    __shared__ __align__(16) float Ks[22][60];
    __shared__ __align__(16) float Vs[22][60];
    const int t  = threadIdx.x;
    const int h0 = blockIdx.x * 16;
    const int bo = blockIdx.y;
    const int o  = bo & 255;
    const float* kp = kmap + (size_t)bo * S;
    const float* vp = vmap + (size_t)bo * S;

    for (int i = t; i < 22 * 56; i += 192) {
        const int row = i / 56, col = i - row * 56;
        const int hh = h0 - 3 + row, ww = col - 3;
        const bool ok = ((unsigned)hh < (unsigned)HH) && ((unsigned)ww < (unsigned)WW);
        Ks[row][col] = ok ? kp[hh * WW + ww] : 0.f;
        Vs[row][col] = ok ? vp[hh * WW + ww] : 0.f;
    }

    const int w0 = (t % 12) * 4;     // output cols w0..w0+3
    const int r  = t / 12;           // 0..15
    const int h  = h0 + r;
    const float4 q4 = *(const float4*)(qmap + (size_t)bo * S + h * WW + w0);
    const float qe[4] = {q4.x * 1.44269504088896340736f,
                         q4.y * 1.44269504088896340736f,
                         q4.z * 1.44269504088896340736f,
                         q4.w * 1.44269504088896340736f};
    const bool ish = (o < 128);
    const float* rp = ish ? (rel_h + o * 7) : (rel_w + (o - 128) * 7);
    float rel[7];
#pragma unroll
    for (int i = 0; i < 7; ++i) rel[i] = rp[i];

    __syncthreads();

    float l[4] = {0.f, 0.f, 0.f, 0.f}, a[4] = {0.f, 0.f, 0.f, 0.f};
#pragma unroll
    for (int kh = 0; kh < KWIN; ++kh) {
        const int rr = r + kh;
        const float4 ka = *(const float4*)&Ks[rr][w0];
        const float4 kb = *(const float4*)&Ks[rr][w0 + 4];
        const float4 kc = *(const float4*)&Ks[rr][w0 + 8];
        const float4 va = *(const float4*)&Vs[rr][w0];
        const float4 vb = *(const float4*)&Vs[rr][w0 + 4];
        const float4 vc = *(const float4*)&Vs[rr][w0 + 8];
        const float ks[12] = {ka.x, ka.y, ka.z, ka.w, kb.x, kb.y, kb.z, kb.w, kc.x, kc.y, kc.z, kc.w};
        const float vs[12] = {va.x, va.y, va.z, va.w, vb.x, vb.y, vb.z, vb.w, vc.x, vc.y, vc.z, vc.w};
        if (ish) {
#pragma unroll
            for (int d = 0; d < 4; ++d) {
                const float bias = qe[d] * rel[kh];
#pragma unroll
                for (int kw = 0; kw < KWIN; ++kw) {
                    const float p = __builtin_amdgcn_exp2f(fmaf(qe[d], ks[d + kw], bias));
                    l[d] += p;
                    a[d] = fmaf(p, vs[d + kw], a[d]);
                }
            }
        } else {
#pragma unroll
            for (int d = 0; d < 4; ++d) {
#pragma unroll
                for (int kw = 0; kw < KWIN; ++kw) {
                    const float p = __builtin_amdgcn_exp2f(fmaf(qe[d], ks[d + kw], qe[d] * rel[kw]));
                    l[d] += p;
                    a[d] = fmaf(p, vs[d + kw], a[d]);
                }
            }
        }
    }
    float4 ov = make_float4(a[0] / l[0], a[1] / l[1], a[2] / l[2], a[3] / l[3]);
    *(float4*)(out + (size_t)bo * S + h * WW + w0) = ov;
}

extern "C" void kernel_launch(void* const* d_in, const int* in_sizes, int n_in,
                              void* d_out, int out_size, void* d_ws, size_t ws_size,
                              hipStream_t stream) {
    const float* x     = (const float*)d_in[0];
    const float* wq    = (const float*)d_in[1];
    const float* wk    = (const float*)d_in[2];
    const float* wv    = (const float*)d_in[3];
    const float* rel_h = (const float*)d_in[4];
    const float* rel_w = (const float*)d_in[5];
    float* out  = (float*)d_out;

    float* kbuf = (float*)d_ws;                             // [B][O][S] f32
    float* vbuf = kbuf + (size_t)BSZ * COUT * S;            // [B][O][S] f32

    dim3 gg(S / 64, COUT / 128, BSZ * 3);                   // (36,2,6)
    qkv_mfma<<<gg, 256, 0, stream>>>(x, wq, wk, wv, out, kbuf, vbuf);

    dim3 g2(HH / 16, BSZ * COUT);                           // (3,512)
    attn_win<<<g2, 192, 0, stream>>>(out, kbuf, vbuf, rel_h, rel_w, out);
}

// Round 7
// 37.691 us; speedup vs baseline: 2.1558x; 1.1293x over previous
//
#include <hip/hip_runtime.h>

#define CIN  256
#define COUT 256
#define BSZ  2
#define HH   48
#define WW   48
#define S    (HH * WW)   // 2304
#define KWIN 7

typedef short  short8 __attribute__((ext_vector_type(8)));
typedef float  f32x4  __attribute__((ext_vector_type(4)));

__device__ inline unsigned cvt_pk_bf16(float f0, float f1) {
    unsigned r;
    asm("v_cvt_pk_bf16_f32 %0, %1, %2" : "=v"(r) : "v"(f0), "v"(f1));
    return r;   // low16 = bf16(f0), high16 = bf16(f1), RNE
}

// ---------- MFMA QKV: D[s][o] = sum_c X[c][s] * W[o][c] ----------
// Block = 64(s) x 128(o) x one (b,m); 4 waves of 64s x 32o. K = 256.
// A (x tile) staged ONCE per block into LDS as bf16 hi + lo residual (shared by
// all 4 waves; was re-split 24x per element in r6). B converted in-loop with
// v_cvt_pk_bf16_f32. Compensation = (ah+al)*bh: exact-x times bf16(w).
__global__ __launch_bounds__(256) void qkv_mfma(
    const float* __restrict__ x,              // [B][C][S]
    const float* __restrict__ wq, const float* __restrict__ wk, const float* __restrict__ wv,
    float* __restrict__ qout, float* __restrict__ kout, float* __restrict__ vout)
{
    __shared__ __align__(16) short Ahi[32][64][8];   // [c8][s][e] 32 KB
    __shared__ __align__(16) short Alo[32][64][8];   // 32 KB
    const int t    = threadIdx.x;
    const int lane = t & 63;
    const int wid  = t >> 6;
    const int r16  = lane & 15;
    const int kq   = lane >> 4;
    const int s0   = blockIdx.x * 64;
    const int o0   = blockIdx.y * 128 + wid * 32;
    const int bm   = blockIdx.z;         // b*3 + m
    const int b    = bm / 3, m = bm % 3;
    const float* wmat = (m == 0) ? wq : (m == 1 ? wk : wv);
    float* outp = ((m == 0) ? qout : (m == 1 ? kout : vout)) + (size_t)b * COUT * S;
    const float* xb = x + (size_t)b * CIN * S + s0;

    // ---- stage A: thread (ss = t&63, cg = t>>6) handles c-chunks cg, cg+4, ..., cg+28
    const int ss = t & 63;
    const int cg = t >> 6;
#pragma unroll 2
    for (int p = 0; p < 8; ++p) {
        const int c8 = cg + p * 4;                   // 0..31
        const float* px = xb + (size_t)(c8 * 8) * S + ss;
        float f[8];
#pragma unroll
        for (int e = 0; e < 8; ++e) f[e] = px[(size_t)e * S];
        union { unsigned u[4]; short8 v; } H, L;
#pragma unroll
        for (int pp = 0; pp < 4; ++pp) {
            H.u[pp] = cvt_pk_bf16(f[2 * pp], f[2 * pp + 1]);
            const float h0 = __uint_as_float(H.u[pp] << 16);
            const float h1 = __uint_as_float(H.u[pp] & 0xFFFF0000u);
            L.u[pp] = cvt_pk_bf16(f[2 * pp] - h0, f[2 * pp + 1] - h1);
        }
        *(short8*)&Ahi[c8][ss][0] = H.v;
        *(short8*)&Alo[c8][ss][0] = L.v;
    }
    __syncthreads();

    f32x4 acc[4][2] = {};
#pragma unroll 2
    for (int kb = 0; kb < 8; ++kb) {
        const int c8 = kb * 4 + kq;
        short8 ah[4], al[4], bh[2];
#pragma unroll
        for (int i = 0; i < 4; ++i) {
            ah[i] = *(const short8*)&Ahi[c8][i * 16 + r16][0];
            al[i] = *(const short8*)&Alo[c8][i * 16 + r16][0];
        }
#pragma unroll
        for (int j = 0; j < 2; ++j) {
            const float* pw = wmat + (size_t)(o0 + j * 16 + r16) * CIN + kb * 32 + kq * 8;
            const float4 wa = *(const float4*)pw;
            const float4 wb = *(const float4*)(pw + 4);
            union { unsigned u[4]; short8 v; } B;
            B.u[0] = cvt_pk_bf16(wa.x, wa.y);
            B.u[1] = cvt_pk_bf16(wa.z, wa.w);
            B.u[2] = cvt_pk_bf16(wb.x, wb.y);
            B.u[3] = cvt_pk_bf16(wb.z, wb.w);
            bh[j] = B.v;
        }
#pragma unroll
        for (int i = 0; i < 4; ++i)
#pragma unroll
            for (int j = 0; j < 2; ++j) {
                acc[i][j] = __builtin_amdgcn_mfma_f32_16x16x32_bf16(ah[i], bh[j], acc[i][j], 0, 0, 0);
                acc[i][j] = __builtin_amdgcn_mfma_f32_16x16x32_bf16(al[i], bh[j], acc[i][j], 0, 0, 0);
            }
    }
#pragma unroll
    for (int i = 0; i < 4; ++i)      // s subtile
#pragma unroll
        for (int j = 0; j < 2; ++j) { // o subtile
            const int o = o0 + j * 16 + r16;
            const int s = s0 + i * 16 + kq * 4;
            float4 r = make_float4(acc[i][j][0], acc[i][j][1], acc[i][j][2], acc[i][j][3]);
            *(float4*)(outp + (size_t)o * S + s) = r;
        }
}

// ---------------- Phase 2: windowed softmax-attention ----------------
// Block = 8 h-rows of one (b,o) plane, 192 thr; thread -> 2 outputs (w0, w0+1).
// 3072 blocks -> ~8 waves/SIMD (was 4.5). Zero-padded LDS halo = reference
// semantics at borders. exp2 with log2e prefolded; v_rcp for the final divide.
__global__ __launch_bounds__(192) void attn_win(
    const float* __restrict__ qmap,   // [B*O][S] (lives in d_out)
    const float* __restrict__ kmap,
    const float* __restrict__ vmap,
    const float* __restrict__ rel_h,
    const float* __restrict__ rel_w,
    float* __restrict__ out)          // same buffer as qmap
{
    __shared__ __align__(16) float Ks[14][60];
    __shared__ __align__(16) float Vs[14][60];
    const int t  = threadIdx.x;
    const int h0 = blockIdx.x * 8;
    const int bo = blockIdx.y;
    const int o  = bo & 255;
    const float* kp = kmap + (size_t)bo * S;
    const float* vp = vmap + (size_t)bo * S;

    for (int i = t; i < 14 * 56; i += 192) {
        const int row = i / 56, col = i - row * 56;
        const int hh = h0 - 3 + row, ww = col - 3;
        const bool ok = ((unsigned)hh < (unsigned)HH) && ((unsigned)ww < (unsigned)WW);
        Ks[row][col] = ok ? kp[hh * WW + ww] : 0.f;
        Vs[row][col] = ok ? vp[hh * WW + ww] : 0.f;
    }

    const int w0 = (t % 24) * 2;     // outputs w0, w0+1
    const int r  = t / 24;           // 0..7
    const int h  = h0 + r;
    const float2 q2 = *(const float2*)(qmap + (size_t)bo * S + h * WW + w0);
    const float qe0 = q2.x * 1.44269504088896340736f;
    const float qe1 = q2.y * 1.44269504088896340736f;
    const bool ish = (o < 128);
    const float* rp = ish ? (rel_h + o * 7) : (rel_w + (o - 128) * 7);
    float rel[7];
#pragma unroll
    for (int i = 0; i < 7; ++i) rel[i] = rp[i];

    __syncthreads();

    float l0 = 0.f, l1 = 0.f, a0 = 0.f, a1 = 0.f;
#pragma unroll
    for (int kh = 0; kh < KWIN; ++kh) {
        const int rr = r + kh;
        float k8[8], v8[8];
#pragma unroll
        for (int n = 0; n < 4; ++n) {
            *(float2*)&k8[2 * n] = *(const float2*)&Ks[rr][w0 + 2 * n];
            *(float2*)&v8[2 * n] = *(const float2*)&Vs[rr][w0 + 2 * n];
        }
        if (ish) {
            const float b0 = qe0 * rel[kh];
            const float b1 = qe1 * rel[kh];
#pragma unroll
            for (int kw = 0; kw < KWIN; ++kw) {
                const float p0 = __builtin_amdgcn_exp2f(fmaf(qe0, k8[kw], b0));
                l0 += p0; a0 = fmaf(p0, v8[kw], a0);
                const float p1 = __builtin_amdgcn_exp2f(fmaf(qe1, k8[kw + 1], b1));
                l1 += p1; a1 = fmaf(p1, v8[kw + 1], a1);
            }
        } else {
#pragma unroll
            for (int kw = 0; kw < KWIN; ++kw) {
                const float p0 = __builtin_amdgcn_exp2f(fmaf(qe0, k8[kw], qe0 * rel[kw]));
                l0 += p0; a0 = fmaf(p0, v8[kw], a0);
                const float p1 = __builtin_amdgcn_exp2f(fmaf(qe1, k8[kw + 1], qe1 * rel[kw]));
                l1 += p1; a1 = fmaf(p1, v8[kw + 1], a1);
            }
        }
    }
    float r0, r1;
    asm("v_rcp_f32 %0, %1" : "=v"(r0) : "v"(l0));
    asm("v_rcp_f32 %0, %1" : "=v"(r1) : "v"(l1));
    float2 ov = make_float2(a0 * r0, a1 * r1);
    *(float2*)(out + (size_t)bo * S + h * WW + w0) = ov;
}

extern "C" void kernel_launch(void* const* d_in, const int* in_sizes, int n_in,
                              void* d_out, int out_size, void* d_ws, size_t ws_size,
                              hipStream_t stream) {
    const float* x     = (const float*)d_in[0];
    const float* wq    = (const float*)d_in[1];
    const float* wk    = (const float*)d_in[2];
    const float* wv    = (const float*)d_in[3];
    const float* rel_h = (const float*)d_in[4];
    const float* rel_w = (const float*)d_in[5];
    float* out  = (float*)d_out;

    float* kbuf = (float*)d_ws;                             // [B][O][S] f32
    float* vbuf = kbuf + (size_t)BSZ * COUT * S;            // [B][O][S] f32

    dim3 gg(S / 64, COUT / 128, BSZ * 3);                   // (36,2,6)
    qkv_mfma<<<gg, 256, 0, stream>>>(x, wq, wk, wv, out, kbuf, vbuf);

    dim3 g2(HH / 8, BSZ * COUT);                            // (6,512)
    attn_win<<<g2, 192, 0, stream>>>(out, kbuf, vbuf, rel_h, rel_w, out);
}